// Round 2
// baseline (459.190 us; speedup 1.0000x reference)
//
#include <hip/hip_runtime.h>
#include <hip/hip_bf16.h>

// x (B=256, R=1024, C=1024) fp32; rows/cols: 64 int32 indices each.
// out = x, except at (b, rows[i], cols[j]) apply mute_msb:
//   if biased exponent E in [127,255) (|x|>=1, finite): set exponent to 126
//   (x -> signed mantissa in [0.5,1)); else identity.
//
// Single fused streaming kernel: grid-stride float4 copy (2.15 GB HBM
// traffic = roofline) + bitmask membership test (masks precomputed into
// d_ws by a tiny kernel; L1-hot during the copy).

#define RR 1024
#define CC 1024

__global__ void build_masks_kernel(const int* __restrict__ rows,
                                   const int* __restrict__ cols,
                                   unsigned* __restrict__ masks, // [64]: 0..31 rowmask, 32..63 colmask
                                   int nr, int nc) {
    int t = threadIdx.x;
    if (t < 64) masks[t] = 0u;
    __syncthreads();
    if (t < nr) {
        int r = rows[t];
        atomicOr(&masks[r >> 5], 1u << (r & 31));
    }
    if (t < nc) {
        int c = cols[t];
        atomicOr(&masks[32 + (c >> 5)], 1u << (c & 31));
    }
}

__global__ void copy_mute_kernel(const float4* __restrict__ x,
                                 float4* __restrict__ out,
                                 const unsigned* __restrict__ masks,
                                 long long nq) {
    long long stride = (long long)gridDim.x * blockDim.x;
    for (long long q = (long long)blockIdx.x * blockDim.x + threadIdx.x;
         q < nq; q += stride) {
        float4 v = x[q];
        // element index e = q*4; r = (e>>10)&1023 = (q>>8)&1023; c = (e&1023)
        int r = (int)((q >> 8) & 1023);
        unsigned rowbit  = (masks[r >> 5] >> (r & 31)) & 1u;
        unsigned colword = masks[32 + (int)((q >> 3) & 31)];
        unsigned colbits = (colword >> (((int)q & 7) * 4)) & 0xFu;
        unsigned m = rowbit ? colbits : 0u;
        if (m) {
            float* f = reinterpret_cast<float*>(&v);
#pragma unroll
            for (int k = 0; k < 4; ++k) {
                if ((m >> k) & 1u) {
                    unsigned u = __float_as_uint(f[k]);
                    unsigned E = (u >> 23) & 0xffu;
                    if (E >= 127u && E < 255u)
                        f[k] = __uint_as_float((u & 0x807fffffu) | (126u << 23));
                }
            }
        }
        out[q] = v;
    }
}

extern "C" void kernel_launch(void* const* d_in, const int* in_sizes, int n_in,
                              void* d_out, int out_size, void* d_ws, size_t ws_size,
                              hipStream_t stream) {
    const float* x  = (const float*)d_in[0];
    const int* rows = (const int*)d_in[1];
    const int* cols = (const int*)d_in[2];
    float* out      = (float*)d_out;
    unsigned* masks = (unsigned*)d_ws;

    const int nr = in_sizes[1];
    const int nc = in_sizes[2];

    build_masks_kernel<<<1, 64, 0, stream>>>(rows, cols, masks, nr, nc);

    long long nq = (long long)in_sizes[0] / 4;  // float4 count
    int block = 256;
    int grid = 2048;  // grid-stride; 8 blocks/CU
    copy_mute_kernel<<<grid, block, 0, stream>>>(
        (const float4*)x, (float4*)out, masks, nq);
}

// Round 4
// 399.625 us; speedup vs baseline: 1.1491x; 1.1491x over previous
//
#include <hip/hip_runtime.h>
#include <hip/hip_bf16.h>

// x (B=256, R=1024, C=1024) fp32; rows/cols: 64 int32 indices each.
// out = x, except at (b, rows[i], cols[j]) apply mute_msb:
//   if biased exponent E in [127,255) (|x|>=1, finite): set exponent to 126
//   (x -> signed mantissa in [0.5,1)); else identity.
//
// Streaming copy at minimal traffic (2.15 GB). Row-per-block decomposition:
// each 256-thread block handles two 1024-float rows per iteration (one float4
// per lane per row). Column membership nibble is loop-invariant per lane
// (register); row membership is one LDS broadcast read. Nontemporal
// load/store (data >> 256 MB L3; avoid cache pollution).

#define RR 1024
#define CC 1024

typedef float f4 __attribute__((ext_vector_type(4)));  // native vector: OK for nontemporal builtins

__global__ void build_masks_kernel(const int* __restrict__ rows,
                                   const int* __restrict__ cols,
                                   unsigned* __restrict__ masks, // [64]: 0..31 row bits, 32..63 col bits
                                   int nr, int nc) {
    int t = threadIdx.x;
    if (t < 64) masks[t] = 0u;
    __syncthreads();
    if (t < nr) {
        int r = rows[t];
        atomicOr(&masks[r >> 5], 1u << (r & 31));
    }
    if (t < nc) {
        int c = cols[t];
        atomicOr(&masks[32 + (c >> 5)], 1u << (c & 31));
    }
}

__device__ __forceinline__ void mute4(f4& v, unsigned m) {
#pragma unroll
    for (int k = 0; k < 4; ++k) {
        if ((m >> k) & 1u) {
            unsigned u = __float_as_uint(v[k]);
            unsigned E = (u >> 23) & 0xffu;
            if (E >= 127u && E < 255u)
                v[k] = __uint_as_float((u & 0x807fffffu) | (126u << 23));
        }
    }
}

__global__ void copy_mute_kernel(const f4* __restrict__ x,
                                 f4* __restrict__ out,
                                 const unsigned* __restrict__ masks,
                                 int nrows) {           // nrows = B * R
    __shared__ unsigned rowmask[32];
    int tid = threadIdx.x;
    if (tid < 32) rowmask[tid] = masks[tid];
    __syncthreads();

    // This lane always handles columns [tid*4, tid*4+4): nibble is invariant.
    unsigned colword = masks[32 + (tid >> 3)];
    unsigned colnib = (colword >> ((tid & 7) * 4)) & 0xFu;

    for (int row = blockIdx.x * 2; row < nrows; row += gridDim.x * 2) {
        long long q0 = (long long)row * 256 + tid;
        f4 v0 = __builtin_nontemporal_load(&x[q0]);
        f4 v1 = __builtin_nontemporal_load(&x[q0 + 256]);

        int r0 = row & (RR - 1);
        int r1 = (row + 1) & (RR - 1);
        unsigned m0 = ((rowmask[r0 >> 5] >> (r0 & 31)) & 1u) ? colnib : 0u;
        unsigned m1 = ((rowmask[r1 >> 5] >> (r1 & 31)) & 1u) ? colnib : 0u;

        if (m0) mute4(v0, m0);
        if (m1) mute4(v1, m1);

        __builtin_nontemporal_store(v0, &out[q0]);
        __builtin_nontemporal_store(v1, &out[q0 + 256]);
    }
}

extern "C" void kernel_launch(void* const* d_in, const int* in_sizes, int n_in,
                              void* d_out, int out_size, void* d_ws, size_t ws_size,
                              hipStream_t stream) {
    const float* x  = (const float*)d_in[0];
    const int* rows = (const int*)d_in[1];
    const int* cols = (const int*)d_in[2];
    float* out      = (float*)d_out;
    unsigned* masks = (unsigned*)d_ws;

    const int nr = in_sizes[1];
    const int nc = in_sizes[2];

    build_masks_kernel<<<1, 64, 0, stream>>>(rows, cols, masks, nr, nc);

    int nrows = in_sizes[0] / CC;   // 262144 (even; grid*2 strides cover all)
    int block = 256;
    int grid = 4096;
    copy_mute_kernel<<<grid, block, 0, stream>>>(
        (const f4*)x, (f4*)out, masks, nrows);
}

// Round 5
// 386.069 us; speedup vs baseline: 1.1894x; 1.0351x over previous
//
#include <hip/hip_runtime.h>
#include <hip/hip_bf16.h>

// x (B=256, R=1024, C=1024) fp32; rows/cols: 64 int32 indices each.
// out = x, except at (b, rows[i], cols[j]) apply mute_msb:
//   if biased exponent E in [127,255) (|x|>=1, finite): set exponent to 126
//   (x -> signed mantissa in [0.5,1)); else identity.
//
// Streaming copy at minimal traffic (2.15 GB). Row-per-block decomposition,
// 4-row unroll, explicit software pipeline (next iteration's loads issued
// before current stores) to keep 4 nontemporal loads in flight per wave.

#define RR 1024
#define CC 1024
#define UNROLL 4

typedef float f4 __attribute__((ext_vector_type(4)));

__global__ void build_masks_kernel(const int* __restrict__ rows,
                                   const int* __restrict__ cols,
                                   unsigned* __restrict__ masks, // [64]: 0..31 row bits, 32..63 col bits
                                   int nr, int nc) {
    int t = threadIdx.x;
    if (t < 64) masks[t] = 0u;
    __syncthreads();
    if (t < nr) {
        int r = rows[t];
        atomicOr(&masks[r >> 5], 1u << (r & 31));
    }
    if (t < nc) {
        int c = cols[t];
        atomicOr(&masks[32 + (c >> 5)], 1u << (c & 31));
    }
}

__device__ __forceinline__ void mute4(f4& v, unsigned m) {
#pragma unroll
    for (int k = 0; k < 4; ++k) {
        if ((m >> k) & 1u) {
            unsigned u = __float_as_uint(v[k]);
            unsigned E = (u >> 23) & 0xffu;
            if (E >= 127u && E < 255u)
                v[k] = __uint_as_float((u & 0x807fffffu) | (126u << 23));
        }
    }
}

__global__ void copy_mute_kernel(const f4* __restrict__ x,
                                 f4* __restrict__ out,
                                 const unsigned* __restrict__ masks,
                                 int nrows) {           // nrows = B * R
    __shared__ unsigned rowmask[32];
    int tid = threadIdx.x;
    if (tid < 32) rowmask[tid] = masks[tid];
    __syncthreads();

    // This lane always handles columns [tid*4, tid*4+4): nibble is invariant.
    unsigned colword = masks[32 + (tid >> 3)];
    unsigned colnib = (colword >> ((tid & 7) * 4)) & 0xFu;

    int rowstride = gridDim.x * UNROLL;               // rows per sweep
    long long qstride = (long long)rowstride * 256;   // f4 units

    int row = blockIdx.x * UNROLL;
    if (row >= nrows) return;
    long long q = (long long)row * 256 + tid;

    f4 v[UNROLL];
#pragma unroll
    for (int k = 0; k < UNROLL; ++k)
        v[k] = __builtin_nontemporal_load(&x[q + k * 256]);

    for (;;) {
        int nrow = row + rowstride;
        bool more = nrow < nrows;
        long long nq = q + qstride;

        f4 n[UNROLL];
        if (more) {
#pragma unroll
            for (int k = 0; k < UNROLL; ++k)
                n[k] = __builtin_nontemporal_load(&x[nq + k * 256]);
        }

#pragma unroll
        for (int k = 0; k < UNROLL; ++k) {
            int r = (row + k) & (RR - 1);
            unsigned m = ((rowmask[r >> 5] >> (r & 31)) & 1u) ? colnib : 0u;
            if (m) mute4(v[k], m);
            __builtin_nontemporal_store(v[k], &out[q + k * 256]);
        }

        if (!more) break;
#pragma unroll
        for (int k = 0; k < UNROLL; ++k) v[k] = n[k];
        row = nrow;
        q = nq;
    }
}

extern "C" void kernel_launch(void* const* d_in, const int* in_sizes, int n_in,
                              void* d_out, int out_size, void* d_ws, size_t ws_size,
                              hipStream_t stream) {
    const float* x  = (const float*)d_in[0];
    const int* rows = (const int*)d_in[1];
    const int* cols = (const int*)d_in[2];
    float* out      = (float*)d_out;
    unsigned* masks = (unsigned*)d_ws;

    const int nr = in_sizes[1];
    const int nc = in_sizes[2];

    build_masks_kernel<<<1, 64, 0, stream>>>(rows, cols, masks, nr, nc);

    int nrows = in_sizes[0] / CC;   // B * R = 262144
    int block = 256;
    int grid = 4096;
    if (grid * UNROLL > nrows) grid = (nrows + UNROLL - 1) / UNROLL;
    copy_mute_kernel<<<grid, block, 0, stream>>>(
        (const f4*)x, (f4*)out, masks, nrows);
}